// Round 8
// baseline (265.992 us; speedup 1.0000x reference)
//
#include <hip/hip_runtime.h>
#include <math.h>

typedef __attribute__((ext_vector_type(8))) short short8;
typedef __attribute__((ext_vector_type(4))) float floatx4;

// Problem constants
#define NB 2
#define SEQ 2048
#define NC 1024
#define NH 16
#define ND 64
#define NF 3072
#define NM 4096  // NB*SEQ
#define KSPLIT 2
#define LSTRIDE (NB * NH * SEQ)

#define SCL 0.18033688011112042f  // 0.125 * log2(e), folded into Q at RoPE time

__device__ __forceinline__ unsigned short f2bf(float f) {
  union { float f; unsigned u; } c; c.f = f;
  unsigned u = c.u;
  u += 0x7fffu + ((u >> 16) & 1u);  // RNE
  return (unsigned short)(u >> 16);
}

__device__ __forceinline__ unsigned pack2bf(float a, float b) {
  unsigned ua = __builtin_bit_cast(unsigned, a) + 0x8000u;
  unsigned ub = __builtin_bit_cast(unsigned, b) + 0x8000u;
  return __builtin_amdgcn_perm(ub, ua, 0x07060302u);
}

// async global->LDS, 16B per lane; LDS dest = wave-uniform base + lane*16 (m97/m104)
__device__ __forceinline__ void gload16(const unsigned short* g, unsigned short* l) {
  __builtin_amdgcn_global_load_lds(
      (const __attribute__((address_space(1))) unsigned int*)g,
      (__attribute__((address_space(3))) unsigned int*)l, 16, 0, 0);
}

// key permutation for register-resident P^T -> PV A-frag alignment
__device__ __forceinline__ int vperm64(int tl) {
  return (tl & 32) | (((tl >> 2) & 3) << 3) | (((tl >> 4) & 1) << 2) | (tl & 3);
}

// ---------------- fused converts + RoPE table ----------------
#define R0 (NM * NC / 4)
#define R1 (NF * NC / 4)
#define R2 (NC * NC / 4)
#define RT (SEQ * 32)
__global__ __launch_bounds__(256) void cvt_all(const float* __restrict__ x,
                                               const float* __restrict__ wq,
                                               const float* __restrict__ wo,
                                               unsigned short* __restrict__ xb,
                                               unsigned short* __restrict__ wqb,
                                               unsigned short* __restrict__ wob,
                                               float2* __restrict__ tab) {
  int i = blockIdx.x * 256 + threadIdx.x;
  if (i >= R0 + R1 + R2) {
    int idx = i - (R0 + R1 + R2);
    int j = idx & 31, t = idx >> 5;
    float inv = exp2f((float)j * (-13.287712379549449f / 32.0f));
    float sn, cs;
    sincosf((float)t * inv, &sn, &cs);
    tab[idx] = make_float2(cs, sn);
    return;
  }
  const float* src;
  unsigned short* dst;
  int off;
  if (i < R0) { src = x; dst = xb; off = i; }
  else if (i < R0 + R1) { src = wq; dst = wqb; off = i - R0; }
  else { src = wo; dst = wob; off = i - R0 - R1; }
  float4 v = ((const float4*)src)[off];
  ushort4 r;
  r.x = f2bf(v.x); r.y = f2bf(v.y); r.z = f2bf(v.z); r.w = f2bf(v.w);
  ((ushort4*)dst)[off] = r;
}

// ---------------- QKV GEMM (unchanged from R7) ----------------
__global__ __launch_bounds__(256) void gemm_qkv(const unsigned short* __restrict__ A,
                                                const unsigned short* __restrict__ B,
                                                unsigned short* __restrict__ qb,
                                                unsigned short* __restrict__ kb,
                                                unsigned short* __restrict__ vt,
                                                const float2* __restrict__ tab,
                                                int M, int N, int K) {
  __shared__ __align__(16) unsigned short As[2][128 * 32];
  __shared__ __align__(16) unsigned short Bs[2][128 * 32];
  const int tid = threadIdx.x, lane = tid & 63, w = tid >> 6;
  const int g = lane & 15, q4 = lane >> 4;
  const int m0 = blockIdx.y * 128, n0 = blockIdx.x * 128;
  const int wm = (w & 1) * 64, wn = (w >> 1) * 64;
  floatx4 acc[4][4];
#pragma unroll
  for (int i = 0; i < 4; i++)
#pragma unroll
    for (int j = 0; j < 4; j++) acc[i][j] = (floatx4)0.0f;
  const int sr = lane & 15, sc = (lane >> 4) * 8;
  const unsigned short* gA = A + (size_t)(m0 + w * 32 + sr) * K + sc;
  const unsigned short* gB = B + (size_t)(n0 + w * 32 + sr) * K + sc;
  const int aoff = w * 1024;
  gload16(gA, &As[0][aoff]);
  gload16(gA + (size_t)16 * K, &As[0][aoff + 512]);
  gload16(gB, &Bs[0][aoff]);
  gload16(gB + (size_t)16 * K, &Bs[0][aoff + 512]);
  __syncthreads();
  const int NIT = K / 32;
  for (int it = 0; it < NIT; it++) {
    const int cur = it & 1;
    if (it < NIT - 1) {
      const int k0 = (it + 1) * 32;
      unsigned short* dA = &As[cur ^ 1][aoff];
      unsigned short* dB = &Bs[cur ^ 1][aoff];
      gload16(gA + k0, dA);
      gload16(gA + (size_t)16 * K + k0, dA + 512);
      gload16(gB + k0, dB);
      gload16(gB + (size_t)16 * K + k0, dB + 512);
    }
    short8 af[4], bfr[4];
#pragma unroll
    for (int mt = 0; mt < 4; mt++)
      af[mt] = *(const short8*)&As[cur][((wm >> 4) + mt) * 512 + q4 * 128 + g * 8];
#pragma unroll
    for (int nt = 0; nt < 4; nt++)
      bfr[nt] = *(const short8*)&Bs[cur][((wn >> 4) + nt) * 512 + q4 * 128 + g * 8];
#pragma unroll
    for (int mt = 0; mt < 4; mt++)
#pragma unroll
      for (int nt = 0; nt < 4; nt++)
        acc[mt][nt] = __builtin_amdgcn_mfma_f32_16x16x32_bf16(af[mt], bfr[nt], acc[mt][nt], 0, 0, 0);
    __syncthreads();
  }
  // fused epilogue: RoPE -> qb(*SCL)/kb ; permuted V^T -> vt
  const int sect = n0 >> 10;                   // 0=q, 1=k, 2=v
  const int colbase = n0 + wn - sect * 1024;
  const int hh = colbase >> 6;
  if (sect < 2) {
    unsigned short* dst = (sect == 0) ? qb : kb;
    const float postscale = (sect == 0) ? SCL : 1.0f;
#pragma unroll
    for (int np = 0; np < 2; np++) {
      const int j = np * 16 + g;
#pragma unroll
      for (int mt = 0; mt < 4; mt++) {
#pragma unroll
        for (int r = 0; r < 4; r++) {
          const int row = m0 + wm + mt * 16 + q4 * 4 + r;
          const int t = row & 2047, b = row >> 11;
          const float2 cs = tab[t * 32 + j];
          const float x1 = acc[mt][np][r], x2 = acc[mt][np + 2][r];
          const size_t o = (((size_t)(b * NH + hh)) * SEQ + t) * ND + j;
          dst[o]      = f2bf((x1 * cs.x - x2 * cs.y) * postscale);
          dst[o + 32] = f2bf((x2 * cs.x + x1 * cs.y) * postscale);
        }
      }
    }
  } else {
#pragma unroll
    for (int nt = 0; nt < 4; nt++) {
      const int d = nt * 16 + g;
#pragma unroll
      for (int mt = 0; mt < 4; mt++) {
#pragma unroll
        for (int r = 0; r < 4; r++) {
          const int row = m0 + wm + mt * 16 + q4 * 4 + r;
          const int t = row & 2047, b = row >> 11;
          const int tp = (t & ~63) | vperm64(t & 63);
          vt[(((size_t)(b * NH + hh)) * ND + d) * SEQ + tp] = f2bf(acc[mt][nt][r]);
        }
      }
    }
  }
}

// ---------------- Flash attention v6: 64 q/wave ----------------
// R5 lesson applied upward: 4 q-16-tiles per wave -> 64 MFMA per 16 ds_read_b128
// per iter (m97-level 4:1 density), attention LDS traffic halved vs v5, and 4
// independent MFMA chains of per-wave ILP. 256 q/block, KSPLIT=2 -> grid 512
// (2 blocks/CU). Q pre-scaled (p=2^st); V pre-permuted; fp32 partials out.
__global__ __launch_bounds__(256, 2) void attn_fwd6(const unsigned short* __restrict__ Qb,
                                                    const unsigned short* __restrict__ Kb,
                                                    const unsigned short* __restrict__ Vt,
                                                    float* __restrict__ Op,
                                                    float* __restrict__ Lp) {
  __shared__ __align__(16) unsigned short Ks[2][64 * 64];
  __shared__ __align__(16) unsigned short Vs[2][64 * 64];
  const int bid = blockIdx.x;
  const int ks = bid & 1, qt = (bid >> 1) & 7, h = (bid >> 4) & 15, b = bid >> 8;
  const int bh = b * NH + h;
  const int tid = threadIdx.x, lane = tid & 63, wave = tid >> 6;
  const int g = lane & 15, q4 = lane >> 4;
  // Q fragments: 4 query-16-tiles per wave
  short8 qa0[4], qa1[4];
#pragma unroll
  for (int j = 0; j < 4; j++) {
    const size_t qrow = ((size_t)bh * SEQ + qt * 256 + wave * 64 + j * 16 + g) * ND;
    qa0[j] = *(const short8*)(Qb + qrow + q4 * 8);
    qa1[j] = *(const short8*)(Qb + qrow + 32 + q4 * 8);
  }
  floatx4 oacc[4][4];
#pragma unroll
  for (int i = 0; i < 4; i++)
#pragma unroll
    for (int j = 0; j < 4; j++) oacc[i][j] = (floatx4)0.0f;
  float lsum[4] = {0.0f, 0.0f, 0.0f, 0.0f};
  const int kq0 = ks * (SEQ / KSPLIT);
  const unsigned short* kg = Kb + (size_t)bh * SEQ * ND + (size_t)(kq0 + wave * 16 + (lane & 15)) * ND + (lane >> 4) * 8;
  const unsigned short* vg = Vt + (size_t)bh * ND * SEQ + (size_t)(wave * 16 + (lane & 15)) * SEQ + kq0 + (lane >> 4) * 8;
  unsigned short* lk0[2] = {&Ks[0][wave * 1024], &Ks[1][wave * 1024]};
  unsigned short* lv0[2] = {&Vs[0][wave * 1024], &Vs[1][wave * 1024]};
  gload16(kg, lk0[0]);
  gload16(kg + 32, lk0[0] + 512);
  gload16(vg, lv0[0]);
  gload16(vg + 32, lv0[0] + 512);
  __syncthreads();
  const int NIT = SEQ / KSPLIT / 64;  // 16
  for (int kt = 0; kt < NIT; kt++) {
    const int cur = kt & 1;
    if (kt < NIT - 1) {
      const unsigned short* kp = kg + (size_t)(kt + 1) * 64 * ND;
      const unsigned short* vp = vg + (kt + 1) * 64;
      unsigned short* dk = lk0[cur ^ 1];
      unsigned short* dv = lv0[cur ^ 1];
      gload16(kp, dk);
      gload16(kp + 32, dk + 512);
      gload16(vp, dv);
      gload16(vp + 32, dv + 512);
    }
    // S^T = K Q^T per nt, exp+pack immediately (keeps live regs small)
    uint pd[4][8];
#pragma unroll
    for (int nt = 0; nt < 4; nt++) {
      short8 kf0 = *(const short8*)&Ks[cur][nt * 1024 + q4 * 128 + g * 8];
      short8 kf1 = *(const short8*)&Ks[cur][nt * 1024 + 512 + q4 * 128 + g * 8];
#pragma unroll
      for (int j = 0; j < 4; j++) {
        floatx4 z = (floatx4)0.0f;
        z = __builtin_amdgcn_mfma_f32_16x16x32_bf16(kf0, qa0[j], z, 0, 0, 0);
        z = __builtin_amdgcn_mfma_f32_16x16x32_bf16(kf1, qa1[j], z, 0, 0, 0);
        float p0 = __builtin_amdgcn_exp2f(z[0]);
        float p1 = __builtin_amdgcn_exp2f(z[1]);
        float p2 = __builtin_amdgcn_exp2f(z[2]);
        float p3 = __builtin_amdgcn_exp2f(z[3]);
        lsum[j] += (p0 + p1) + (p2 + p3);
        pd[j][nt * 2]     = pack2bf(p0, p1);
        pd[j][nt * 2 + 1] = pack2bf(p2, p3);
      }
    }
    short8 Bq0[4], Bq1[4];
#pragma unroll
    for (int j = 0; j < 4; j++) {
      Bq0[j] = short8{(short)pd[j][0], (short)(pd[j][0] >> 16), (short)pd[j][1], (short)(pd[j][1] >> 16),
                      (short)pd[j][2], (short)(pd[j][2] >> 16), (short)pd[j][3], (short)(pd[j][3] >> 16)};
      Bq1[j] = short8{(short)pd[j][4], (short)(pd[j][4] >> 16), (short)pd[j][5], (short)(pd[j][5] >> 16),
                      (short)pd[j][6], (short)(pd[j][6] >> 16), (short)pd[j][7], (short)(pd[j][7] >> 16)};
    }
    // O^T += V^T P^T (va shared by all 4 q-tiles)
#pragma unroll
    for (int dt = 0; dt < 4; dt++) {
      short8 va0 = *(const short8*)&Vs[cur][dt * 1024 + q4 * 128 + g * 8];
      short8 va1 = *(const short8*)&Vs[cur][dt * 1024 + 512 + q4 * 128 + g * 8];
#pragma unroll
      for (int j = 0; j < 4; j++) {
        oacc[j][dt] = __builtin_amdgcn_mfma_f32_16x16x32_bf16(va0, Bq0[j], oacc[j][dt], 0, 0, 0);
        oacc[j][dt] = __builtin_amdgcn_mfma_f32_16x16x32_bf16(va1, Bq1[j], oacc[j][dt], 0, 0, 0);
      }
    }
    __syncthreads();
  }
  // partial-l reduce + fp32 partial writes
  float* op = Op + (size_t)ks * NM * NC;
  float* lp = Lp + (size_t)ks * LSTRIDE + (size_t)bh * SEQ;
#pragma unroll
  for (int j = 0; j < 4; j++) {
    float ls = lsum[j];
    ls += __shfl_xor(ls, 16, 64);
    ls += __shfl_xor(ls, 32, 64);
    const int tq = qt * 256 + wave * 64 + j * 16 + g;
    float* o0 = op + ((size_t)b * SEQ + tq) * NC + h * ND + q4 * 4;
#pragma unroll
    for (int dt = 0; dt < 4; dt++)
      *(float4*)(o0 + dt * 16) = make_float4(oacc[j][dt][0], oacc[j][dt][1], oacc[j][dt][2], oacc[j][dt][3]);
    if (q4 == 0) lp[tq] = ls;
  }
}

// ---------------- out-proj GEMM with fused split-K combine ----------------
// out[M,N] = ((Op0+Op1)/(l0+l1)) @ Wout^T + bout. A staged via VGPR loads of
// fp32 partials (combine+cvt in-register, ds_write); B via gload16 dbuf.
// Kills the attn_cmb pass and the ob bf16 round-trip.
__global__ __launch_bounds__(256) void gemm_out(const float* __restrict__ Op,
                                                const float* __restrict__ Lp,
                                                const unsigned short* __restrict__ Bw,
                                                const float* __restrict__ bias,
                                                float* __restrict__ C) {
  const int M = NM, N = NC, K = NC;
  __shared__ __align__(16) unsigned short As[2][128 * 32];
  __shared__ __align__(16) unsigned short Bs[2][64 * 32];
  const int tid = threadIdx.x, lane = tid & 63, w = tid >> 6;
  const int g = lane & 15, q4 = lane >> 4;
  const int m0 = blockIdx.y * 128, n0 = blockIdx.x * 64;
  const int wm = (w & 1) * 64, wn = (w >> 1) * 32;
  floatx4 acc[4][2];
#pragma unroll
  for (int i = 0; i < 4; i++)
#pragma unroll
    for (int j = 0; j < 2; j++) acc[i][j] = (floatx4)0.0f;
  const int sr = lane & 15, sc = (lane >> 4) * 8;
  const int r0 = m0 + w * 32 + sr, r1 = r0 + 16;
  const int b0r = r0 >> 11, t0 = r0 & 2047;
  const int b1r = r1 >> 11, t1 = r1 & 2047;
  const float* gA0 = Op + (size_t)r0 * NC + sc;
  const float* gA1 = Op + (size_t)r1 * NC + sc;
  const unsigned short* gB = Bw + (size_t)(n0 + w * 16 + sr) * K + sc;
  const int aoff = w * 1024, boff = w * 512;
  const size_t l0base = (size_t)(b0r * NH) * SEQ + t0;
  const size_t l1base = (size_t)(b1r * NH) * SEQ + t1;

  // staging helper (combine + cvt + pack to LDS)
  auto stageA = [&](int k0, int buf) {
    const int hh = k0 >> 6;
    float4 a00 = *(const float4*)(gA0 + k0);
    float4 a01 = *(const float4*)(gA0 + k0 + 4);
    float4 d00 = *(const float4*)(gA0 + (size_t)NM * NC + k0);
    float4 d01 = *(const float4*)(gA0 + (size_t)NM * NC + k0 + 4);
    float4 a10 = *(const float4*)(gA1 + k0);
    float4 a11 = *(const float4*)(gA1 + k0 + 4);
    float4 d10 = *(const float4*)(gA1 + (size_t)NM * NC + k0);
    float4 d11 = *(const float4*)(gA1 + (size_t)NM * NC + k0 + 4);
    const size_t li0 = l0base + (size_t)hh * SEQ;
    const size_t li1 = l1base + (size_t)hh * SEQ;
    const float iv0 = 1.0f / (Lp[li0] + Lp[(size_t)LSTRIDE + li0]);
    const float iv1 = 1.0f / (Lp[li1] + Lp[(size_t)LSTRIDE + li1]);
    uint4 w0, w1;
    w0.x = pack2bf((a00.x + d00.x) * iv0, (a00.y + d00.y) * iv0);
    w0.y = pack2bf((a00.z + d00.z) * iv0, (a00.w + d00.w) * iv0);
    w0.z = pack2bf((a01.x + d01.x) * iv0, (a01.y + d01.y) * iv0);
    w0.w = pack2bf((a01.z + d01.z) * iv0, (a01.w + d01.w) * iv0);
    w1.x = pack2bf((a10.x + d10.x) * iv1, (a10.y + d10.y) * iv1);
    w1.y = pack2bf((a10.z + d10.z) * iv1, (a10.w + d10.w) * iv1);
    w1.z = pack2bf((a11.x + d11.x) * iv1, (a11.y + d11.y) * iv1);
    w1.w = pack2bf((a11.z + d11.z) * iv1, (a11.w + d11.w) * iv1);
    *(uint4*)&As[buf][aoff + (lane >> 4) * 128 + sr * 8] = w0;
    *(uint4*)&As[buf][aoff + 512 + (lane >> 4) * 128 + sr * 8] = w1;
  };

  // prologue: stage it=0
  gload16(gB, &Bs[0][boff]);
  stageA(0, 0);
  __syncthreads();
  const int NIT = K / 32;  // 32
  for (int it = 0; it < NIT; it++) {
    const int cur = it & 1;
    if (it < NIT - 1) gload16(gB + (it + 1) * 32, &Bs[cur ^ 1][boff]);
    short8 af[4], bfr[2];
#pragma unroll
    for (int mt = 0; mt < 4; mt++)
      af[mt] = *(const short8*)&As[cur][((wm >> 4) + mt) * 512 + q4 * 128 + g * 8];
#pragma unroll
    for (int nt = 0; nt < 2; nt++)
      bfr[nt] = *(const short8*)&Bs[cur][((wn >> 4) + nt) * 512 + q4 * 128 + g * 8];
#pragma unroll
    for (int mt = 0; mt < 4; mt++)
#pragma unroll
      for (int nt = 0; nt < 2; nt++)
        acc[mt][nt] = __builtin_amdgcn_mfma_f32_16x16x32_bf16(af[mt], bfr[nt], acc[mt][nt], 0, 0, 0);
    if (it < NIT - 1) stageA((it + 1) * 32, cur ^ 1);
    __syncthreads();
  }
  // epilogue: fp32 C + bias
#pragma unroll
  for (int nt = 0; nt < 2; nt++) {
    const int col = n0 + wn + nt * 16 + g;
    const float bv = bias[col];
#pragma unroll
    for (int mt = 0; mt < 4; mt++) {
      const int row = m0 + wm + mt * 16 + q4 * 4;
#pragma unroll
      for (int r = 0; r < 4; r++)
        C[(size_t)(row + r) * N + col] = acc[mt][nt][r] + bv;
    }
  }
}

extern "C" void kernel_launch(void* const* d_in, const int* in_sizes, int n_in,
                              void* d_out, int out_size, void* d_ws, size_t ws_size,
                              hipStream_t stream) {
  const float* x    = (const float*)d_in[0];
  const float* Wqkv = (const float*)d_in[1];
  const float* Wout = (const float*)d_in[2];
  const float* bout = (const float*)d_in[3];
  float* out = (float*)d_out;

  char* ws = (char*)d_ws;
  unsigned short* xb    = (unsigned short*)ws;          // 4096x1024 bf16
  unsigned short* wqkvb = xb + (size_t)NM * NC;         // 3072x1024 bf16
  unsigned short* woutb = wqkvb + (size_t)NF * NC;      // 1024x1024 bf16
  unsigned short* qb    = woutb + (size_t)NC * NC;      // [b,h,t,d] bf16, pre-scaled SCL
  unsigned short* kb    = qb + (size_t)NM * NC;         // [b,h,t,d] bf16
  unsigned short* vt    = kb + (size_t)NM * NC;         // [b,h,d,pi(t)] bf16
  float2* tab           = (float2*)(vt + (size_t)NM * NC);    // 2048x32 (cos,sin)
  float* Op             = (float*)(tab + SEQ * 32);           // 2 x [NM,NC] fp32 partials
  float* Lp             = Op + (size_t)KSPLIT * NM * NC;      // 2 x [NB*NH,SEQ] fp32

  cvt_all<<<(R0 + R1 + R2 + RT) / 256, 256, 0, stream>>>(x, Wqkv, Wout, xb, wqkvb, woutb, tab);
  gemm_qkv<<<dim3(NF / 128, NM / 128), 256, 0, stream>>>(
      xb, wqkvb, qb, kb, vt, tab, NM, NF, NC);
  attn_fwd6<<<NB * NH * (SEQ / 256) * KSPLIT, 256, 0, stream>>>(qb, kb, vt, Op, Lp);
  gemm_out<<<dim3(NC / 64, NM / 128), 256, 0, stream>>>(Op, Lp, woutb, bout, out);
}

// Round 9
// 238.070 us; speedup vs baseline: 1.1173x; 1.1173x over previous
//
#include <hip/hip_runtime.h>
#include <math.h>

typedef __attribute__((ext_vector_type(8))) short short8;
typedef __attribute__((ext_vector_type(4))) float floatx4;

// Problem constants
#define NB 2
#define SEQ 2048
#define NC 1024
#define NH 16
#define ND 64
#define NF 3072
#define NM 4096  // NB*SEQ
#define KSPLIT 2
#define LSTRIDE (NB * NH * SEQ)

#define SCL 0.18033688011112042f  // 0.125 * log2(e), folded into Q at RoPE time

__device__ __forceinline__ unsigned short f2bf(float f) {
  union { float f; unsigned u; } c; c.f = f;
  unsigned u = c.u;
  u += 0x7fffu + ((u >> 16) & 1u);  // RNE
  return (unsigned short)(u >> 16);
}

__device__ __forceinline__ unsigned pack2bf(float a, float b) {
  unsigned ua = __builtin_bit_cast(unsigned, a) + 0x8000u;
  unsigned ub = __builtin_bit_cast(unsigned, b) + 0x8000u;
  return __builtin_amdgcn_perm(ub, ua, 0x07060302u);
}

// async global->LDS, 16B per lane; LDS dest = wave-uniform base + lane*16 (m97/m104)
__device__ __forceinline__ void gload16(const unsigned short* g, unsigned short* l) {
  __builtin_amdgcn_global_load_lds(
      (const __attribute__((address_space(1))) unsigned int*)g,
      (__attribute__((address_space(3))) unsigned int*)l, 16, 0, 0);
}

// key permutation for register-resident P^T -> PV A-frag alignment
__device__ __forceinline__ int vperm64(int tl) {
  return (tl & 32) | (((tl >> 2) & 3) << 3) | (((tl >> 4) & 1) << 2) | (tl & 3);
}

// ---------------- fused converts + RoPE table ----------------
#define R0 (NM * NC / 4)
#define R1 (NF * NC / 4)
#define R2 (NC * NC / 4)
#define RT (SEQ * 32)
__global__ __launch_bounds__(256) void cvt_all(const float* __restrict__ x,
                                               const float* __restrict__ wq,
                                               const float* __restrict__ wo,
                                               unsigned short* __restrict__ xb,
                                               unsigned short* __restrict__ wqb,
                                               unsigned short* __restrict__ wob,
                                               float2* __restrict__ tab) {
  int i = blockIdx.x * 256 + threadIdx.x;
  if (i >= R0 + R1 + R2) {
    int idx = i - (R0 + R1 + R2);
    int j = idx & 31, t = idx >> 5;
    float inv = exp2f((float)j * (-13.287712379549449f / 32.0f));
    float sn, cs;
    sincosf((float)t * inv, &sn, &cs);
    tab[idx] = make_float2(cs, sn);
    return;
  }
  const float* src;
  unsigned short* dst;
  int off;
  if (i < R0) { src = x; dst = xb; off = i; }
  else if (i < R0 + R1) { src = wq; dst = wqb; off = i - R0; }
  else { src = wo; dst = wob; off = i - R0 - R1; }
  float4 v = ((const float4*)src)[off];
  ushort4 r;
  r.x = f2bf(v.x); r.y = f2bf(v.y); r.z = f2bf(v.z); r.w = f2bf(v.w);
  ((ushort4*)dst)[off] = r;
}

// ---------------- GEMM v3: templated tile, dbuf DMA staging ----------------
// R8 lesson: staging mechanism doesn't matter at 3 blocks/CU — latency-bound.
// R9 lever: smaller BM -> 2x grid -> 6 (QKV) / 4 (out-proj) blocks per CU so
// co-resident blocks cover the ~900cyc HBM load latency at each barrier drain.
// LDS chunk-transposed (0 conflicts). EPI=0: fp32 C+bias. EPI=1: RoPE/V^T fused.
template <int BM, int BN, int EPI, int MINW>
__global__ __launch_bounds__(256, MINW) void gemm_t(const unsigned short* __restrict__ A,
                                                    const unsigned short* __restrict__ B,
                                                    float* __restrict__ C,
                                                    const float* __restrict__ bias,
                                                    unsigned short* __restrict__ qb,
                                                    unsigned short* __restrict__ kb,
                                                    unsigned short* __restrict__ vt,
                                                    const float2* __restrict__ tab,
                                                    int M, int N, int K) {
  constexpr int MT = BM / 32;  // m-tiles per wave
  constexpr int NT = BN / 32;  // n-tiles per wave
  constexpr int AC = BM / 64;  // A gload16 chunks per wave
  constexpr int BC = BN / 64;  // B gload16 chunks per wave
  __shared__ __align__(16) unsigned short As[2][BM * 32];
  __shared__ __align__(16) unsigned short Bs[2][BN * 32];
  const int tid = threadIdx.x, lane = tid & 63, w = tid >> 6;
  const int g = lane & 15, q4 = lane >> 4;
  const int m0 = blockIdx.y * BM, n0 = blockIdx.x * BN;
  const int wm = (w & 1) * (BM / 2), wn = (w >> 1) * (BN / 2);
  floatx4 acc[MT][NT];
#pragma unroll
  for (int i = 0; i < MT; i++)
#pragma unroll
    for (int j = 0; j < NT; j++) acc[i][j] = (floatx4)0.0f;
  const int sr = lane & 15, sc = (lane >> 4) * 8;
  const unsigned short* gA = A + (size_t)(m0 + w * (BM / 4) + sr) * K + sc;
  const unsigned short* gB = B + (size_t)(n0 + w * (BN / 4) + sr) * K + sc;
  const int aoff = w * (BM / 4) * 32;
  const int boff = w * (BN / 4) * 32;
#pragma unroll
  for (int c = 0; c < AC; c++) gload16(gA + (size_t)c * 16 * K, &As[0][aoff + c * 512]);
#pragma unroll
  for (int c = 0; c < BC; c++) gload16(gB + (size_t)c * 16 * K, &Bs[0][boff + c * 512]);
  __syncthreads();
  const int NIT = K / 32;
  for (int it = 0; it < NIT; it++) {
    const int cur = it & 1;
    if (it < NIT - 1) {
      const int k0 = (it + 1) * 32;
#pragma unroll
      for (int c = 0; c < AC; c++) gload16(gA + (size_t)c * 16 * K + k0, &As[cur ^ 1][aoff + c * 512]);
#pragma unroll
      for (int c = 0; c < BC; c++) gload16(gB + (size_t)c * 16 * K + k0, &Bs[cur ^ 1][boff + c * 512]);
    }
    short8 af[MT], bfr[NT];
#pragma unroll
    for (int mt = 0; mt < MT; mt++)
      af[mt] = *(const short8*)&As[cur][((wm >> 4) + mt) * 512 + q4 * 128 + g * 8];
#pragma unroll
    for (int nt = 0; nt < NT; nt++)
      bfr[nt] = *(const short8*)&Bs[cur][((wn >> 4) + nt) * 512 + q4 * 128 + g * 8];
#pragma unroll
    for (int mt = 0; mt < MT; mt++)
#pragma unroll
      for (int nt = 0; nt < NT; nt++)
        acc[mt][nt] = __builtin_amdgcn_mfma_f32_16x16x32_bf16(af[mt], bfr[nt], acc[mt][nt], 0, 0, 0);
    __syncthreads();
  }
  // C/D layout: col = lane&15, row = (lane>>4)*4 + reg (verified m89/m91)
  if constexpr (EPI == 0) {
#pragma unroll
    for (int nt = 0; nt < NT; nt++) {
      const int col = n0 + wn + nt * 16 + g;
      const float bv = bias ? bias[col] : 0.0f;
#pragma unroll
      for (int mt = 0; mt < MT; mt++) {
        const int row = m0 + wm + mt * 16 + q4 * 4;
#pragma unroll
        for (int r = 0; r < 4; r++)
          C[(size_t)(row + r) * N + col] = acc[mt][nt][r] + bv;
      }
    }
  } else {
    // QKV epilogue (requires BN=128: wn-tile of 64 cols == one head)
    const int sect = n0 >> 10;                   // 0=q, 1=k, 2=v
    const int colbase = n0 + wn - sect * 1024;
    const int hh = colbase >> 6;
    if (sect < 2) {
      unsigned short* dst = (sect == 0) ? qb : kb;
      const float postscale = (sect == 0) ? SCL : 1.0f;
#pragma unroll
      for (int np = 0; np < 2; np++) {
        const int j = np * 16 + g;
#pragma unroll
        for (int mt = 0; mt < MT; mt++) {
#pragma unroll
          for (int r = 0; r < 4; r++) {
            const int row = m0 + wm + mt * 16 + q4 * 4 + r;
            const int t = row & 2047, b = row >> 11;
            const float2 cs = tab[t * 32 + j];
            const float x1 = acc[mt][np][r], x2 = acc[mt][np + 2][r];
            const size_t o = (((size_t)(b * NH + hh)) * SEQ + t) * ND + j;
            dst[o]      = f2bf((x1 * cs.x - x2 * cs.y) * postscale);
            dst[o + 32] = f2bf((x2 * cs.x + x1 * cs.y) * postscale);
          }
        }
      }
    } else {
#pragma unroll
      for (int nt = 0; nt < NT; nt++) {
        const int d = nt * 16 + g;
#pragma unroll
        for (int mt = 0; mt < MT; mt++) {
#pragma unroll
          for (int r = 0; r < 4; r++) {
            const int row = m0 + wm + mt * 16 + q4 * 4 + r;
            const int t = row & 2047, b = row >> 11;
            const int tp = (t & ~63) | vperm64(t & 63);
            vt[(((size_t)(b * NH + hh)) * ND + d) * SEQ + tp] = f2bf(acc[mt][nt][r]);
          }
        }
      }
    }
  }
}

// ---------------- Flash attention v6: 64 q/wave (unchanged from R8) ----------------
__global__ __launch_bounds__(256, 2) void attn_fwd6(const unsigned short* __restrict__ Qb,
                                                    const unsigned short* __restrict__ Kb,
                                                    const unsigned short* __restrict__ Vt,
                                                    float* __restrict__ Op,
                                                    float* __restrict__ Lp) {
  __shared__ __align__(16) unsigned short Ks[2][64 * 64];
  __shared__ __align__(16) unsigned short Vs[2][64 * 64];
  const int bid = blockIdx.x;
  const int ks = bid & 1, qt = (bid >> 1) & 7, h = (bid >> 4) & 15, b = bid >> 8;
  const int bh = b * NH + h;
  const int tid = threadIdx.x, lane = tid & 63, wave = tid >> 6;
  const int g = lane & 15, q4 = lane >> 4;
  short8 qa0[4], qa1[4];
#pragma unroll
  for (int j = 0; j < 4; j++) {
    const size_t qrow = ((size_t)bh * SEQ + qt * 256 + wave * 64 + j * 16 + g) * ND;
    qa0[j] = *(const short8*)(Qb + qrow + q4 * 8);
    qa1[j] = *(const short8*)(Qb + qrow + 32 + q4 * 8);
  }
  floatx4 oacc[4][4];
#pragma unroll
  for (int i = 0; i < 4; i++)
#pragma unroll
    for (int j = 0; j < 4; j++) oacc[i][j] = (floatx4)0.0f;
  float lsum[4] = {0.0f, 0.0f, 0.0f, 0.0f};
  const int kq0 = ks * (SEQ / KSPLIT);
  const unsigned short* kg = Kb + (size_t)bh * SEQ * ND + (size_t)(kq0 + wave * 16 + (lane & 15)) * ND + (lane >> 4) * 8;
  const unsigned short* vg = Vt + (size_t)bh * ND * SEQ + (size_t)(wave * 16 + (lane & 15)) * SEQ + kq0 + (lane >> 4) * 8;
  unsigned short* lk0[2] = {&Ks[0][wave * 1024], &Ks[1][wave * 1024]};
  unsigned short* lv0[2] = {&Vs[0][wave * 1024], &Vs[1][wave * 1024]};
  gload16(kg, lk0[0]);
  gload16(kg + 32, lk0[0] + 512);
  gload16(vg, lv0[0]);
  gload16(vg + 32, lv0[0] + 512);
  __syncthreads();
  const int NIT = SEQ / KSPLIT / 64;  // 16
  for (int kt = 0; kt < NIT; kt++) {
    const int cur = kt & 1;
    if (kt < NIT - 1) {
      const unsigned short* kp = kg + (size_t)(kt + 1) * 64 * ND;
      const unsigned short* vp = vg + (kt + 1) * 64;
      unsigned short* dk = lk0[cur ^ 1];
      unsigned short* dv = lv0[cur ^ 1];
      gload16(kp, dk);
      gload16(kp + 32, dk + 512);
      gload16(vp, dv);
      gload16(vp + 32, dv + 512);
    }
    uint pd[4][8];
#pragma unroll
    for (int nt = 0; nt < 4; nt++) {
      short8 kf0 = *(const short8*)&Ks[cur][nt * 1024 + q4 * 128 + g * 8];
      short8 kf1 = *(const short8*)&Ks[cur][nt * 1024 + 512 + q4 * 128 + g * 8];
#pragma unroll
      for (int j = 0; j < 4; j++) {
        floatx4 z = (floatx4)0.0f;
        z = __builtin_amdgcn_mfma_f32_16x16x32_bf16(kf0, qa0[j], z, 0, 0, 0);
        z = __builtin_amdgcn_mfma_f32_16x16x32_bf16(kf1, qa1[j], z, 0, 0, 0);
        float p0 = __builtin_amdgcn_exp2f(z[0]);
        float p1 = __builtin_amdgcn_exp2f(z[1]);
        float p2 = __builtin_amdgcn_exp2f(z[2]);
        float p3 = __builtin_amdgcn_exp2f(z[3]);
        lsum[j] += (p0 + p1) + (p2 + p3);
        pd[j][nt * 2]     = pack2bf(p0, p1);
        pd[j][nt * 2 + 1] = pack2bf(p2, p3);
      }
    }
    short8 Bq0[4], Bq1[4];
#pragma unroll
    for (int j = 0; j < 4; j++) {
      Bq0[j] = short8{(short)pd[j][0], (short)(pd[j][0] >> 16), (short)pd[j][1], (short)(pd[j][1] >> 16),
                      (short)pd[j][2], (short)(pd[j][2] >> 16), (short)pd[j][3], (short)(pd[j][3] >> 16)};
      Bq1[j] = short8{(short)pd[j][4], (short)(pd[j][4] >> 16), (short)pd[j][5], (short)(pd[j][5] >> 16),
                      (short)pd[j][6], (short)(pd[j][6] >> 16), (short)pd[j][7], (short)(pd[j][7] >> 16)};
    }
#pragma unroll
    for (int dt = 0; dt < 4; dt++) {
      short8 va0 = *(const short8*)&Vs[cur][dt * 1024 + q4 * 128 + g * 8];
      short8 va1 = *(const short8*)&Vs[cur][dt * 1024 + 512 + q4 * 128 + g * 8];
#pragma unroll
      for (int j = 0; j < 4; j++) {
        oacc[j][dt] = __builtin_amdgcn_mfma_f32_16x16x32_bf16(va0, Bq0[j], oacc[j][dt], 0, 0, 0);
        oacc[j][dt] = __builtin_amdgcn_mfma_f32_16x16x32_bf16(va1, Bq1[j], oacc[j][dt], 0, 0, 0);
      }
    }
    __syncthreads();
  }
  float* op = Op + (size_t)ks * NM * NC;
  float* lp = Lp + (size_t)ks * LSTRIDE + (size_t)bh * SEQ;
#pragma unroll
  for (int j = 0; j < 4; j++) {
    float ls = lsum[j];
    ls += __shfl_xor(ls, 16, 64);
    ls += __shfl_xor(ls, 32, 64);
    const int tq = qt * 256 + wave * 64 + j * 16 + g;
    float* o0 = op + ((size_t)b * SEQ + tq) * NC + h * ND + q4 * 4;
#pragma unroll
    for (int dt = 0; dt < 4; dt++)
      *(float4*)(o0 + dt * 16) = make_float4(oacc[j][dt][0], oacc[j][dt][1], oacc[j][dt][2], oacc[j][dt][3]);
    if (q4 == 0) lp[tq] = ls;
  }
}

// ---------------- split-K combine: ob = (O0+O1)/(l0+l1), bf16 (R7 revert) ----------------
__global__ __launch_bounds__(256) void attn_cmb(const float* __restrict__ Op,
                                                const float* __restrict__ Lp,
                                                unsigned short* __restrict__ Ob) {
  int i = blockIdx.x * 256 + threadIdx.x;
  const int row = i >> 8;
  const int c = (i & 255) * 4;
  const int b = row >> 11, t = row & 2047, h = c >> 6;
  const size_t lidx = (size_t)(b * NH + h) * SEQ + t;
  const float l = Lp[lidx] + Lp[(size_t)LSTRIDE + lidx];
  const float iv = 1.0f / l;
  float4 a = ((const float4*)Op)[i];
  float4 d = ((const float4*)(Op + (size_t)NM * NC))[i];
  ushort4 r;
  r.x = f2bf((a.x + d.x) * iv);
  r.y = f2bf((a.y + d.y) * iv);
  r.z = f2bf((a.z + d.z) * iv);
  r.w = f2bf((a.w + d.w) * iv);
  ((ushort4*)Ob)[i] = r;
}

extern "C" void kernel_launch(void* const* d_in, const int* in_sizes, int n_in,
                              void* d_out, int out_size, void* d_ws, size_t ws_size,
                              hipStream_t stream) {
  const float* x    = (const float*)d_in[0];
  const float* Wqkv = (const float*)d_in[1];
  const float* Wout = (const float*)d_in[2];
  const float* bout = (const float*)d_in[3];
  float* out = (float*)d_out;

  char* ws = (char*)d_ws;
  unsigned short* xb    = (unsigned short*)ws;          // 4096x1024 bf16
  unsigned short* wqkvb = xb + (size_t)NM * NC;         // 3072x1024 bf16
  unsigned short* woutb = wqkvb + (size_t)NF * NC;      // 1024x1024 bf16
  unsigned short* qb    = woutb + (size_t)NC * NC;      // [b,h,t,d] bf16, pre-scaled SCL
  unsigned short* kb    = qb + (size_t)NM * NC;         // [b,h,t,d] bf16
  unsigned short* vt    = kb + (size_t)NM * NC;         // [b,h,d,pi(t)] bf16
  unsigned short* ob    = vt + (size_t)NM * NC;         // [b,t,c] bf16
  float2* tab           = (float2*)(ob + (size_t)NM * NC);    // 2048x32 (cos,sin)
  float* Op             = (float*)(tab + SEQ * 32);           // 2 x [NM,NC] fp32 partials
  float* Lp             = Op + (size_t)KSPLIT * NM * NC;      // 2 x [NB*NH,SEQ] fp32

  cvt_all<<<(R0 + R1 + R2 + RT) / 256, 256, 0, stream>>>(x, Wqkv, Wout, xb, wqkvb, woutb, tab);
  // QKV: 64x128 tile -> grid 1536 = 6 blocks/CU
  gemm_t<64, 128, 1, 6><<<dim3(NF / 128, NM / 64), 256, 0, stream>>>(
      xb, wqkvb, nullptr, nullptr, qb, kb, vt, tab, NM, NF, NC);
  attn_fwd6<<<NB * NH * (SEQ / 256) * KSPLIT, 256, 0, stream>>>(qb, kb, vt, Op, Lp);
  attn_cmb<<<(NM * NC / 4) / 256, 256, 0, stream>>>(Op, Lp, ob);
  // out-proj: 64x64 tile -> grid 1024 = 4 blocks/CU
  gemm_t<64, 64, 0, 4><<<dim3(NC / 64, NM / 64), 256, 0, stream>>>(
      ob, woutb, out, bout, nullptr, nullptr, nullptr, nullptr, NM, NC, NC);
}